// Round 1
// 481.890 us; speedup vs baseline: 1.0512x; 1.0512x over previous
//
#include <hip/hip_runtime.h>

// =====================================================================
// GraphAutoEncoder forward (all fp32). GCN via CSR build + gather.
// R8: parallel scan fixed the build chain. R9: node tile 64, KC 16 ->
// 782+ blocks (~3/CU). R10: gemm was stall-bound (VALUBusy 36%,
// occupancy 21%): staging loads were issued inside the barrier interval
// they're consumed in. Now register-double-buffered: next tile's global
// loads issue right after the first barrier and drain during compute.
// Also: each thread owns 4 CONTIGUOUS nodes so the per-k A-fragment is
// one ds_read_b128 (2-way bank alias = free) instead of 4 strided b32.
// =====================================================================

constexpr int NBLK = 128;           // scatter blocks (chunk = E/128)
constexpr int GRP  = NBLK / 8;      // block-groups per XCD residue

// ---------------- GEMM: C[:,foff:foff+MT] = act(A @ W^T + b) ---------
// node tile = 64 (TN=4 contiguous), KC=16, MT per blockIdx.y.
template <int K, int MT, int M, int ACT, bool BIAS>  // ACT: 0 none,1 relu,2 sigmoid
__global__ __launch_bounds__(256) void gemm_rt(const float* __restrict__ A,
                                               const float* __restrict__ W,
                                               const float* __restrict__ bias,
                                               float* __restrict__ C, int N) {
    constexpr int KC  = 16;
    constexpr int NT  = 64;
    constexpr int TM  = MT / 16;   // 8 (MT=128) or 4 (MT=64)
    constexpr int TN  = 4;
    constexpr int WLD = MT / 64;   // float4 W-loads per thread per stage
    __shared__ float As[KC][NT + 4];
    __shared__ float Ws[KC][MT + 4];

    const int tid  = threadIdx.x;
    const int tx   = tid & 15;
    const int ty   = tid >> 4;
    const int nodeBase = blockIdx.x * NT;
    const int foff     = blockIdx.y * MT;

    // staging coords: thread loads A[gn][sk..sk+3] and W[foff+sm_i][sk..sk+3]
    const int sn = tid >> 2;          // 0..63
    const int sk = (tid & 3) * 4;     // 0,4,8,12
    const int gn = nodeBase + sn;
    const bool aval = gn < N;
    const float* aptr = A + (size_t)gn * K + sk;

    float acc[TN][TM];
#pragma unroll
    for (int i = 0; i < TN; ++i)
#pragma unroll
        for (int j = 0; j < TM; ++j) acc[i][j] = 0.f;

    float4 a_reg = make_float4(0.f, 0.f, 0.f, 0.f);
    float4 w_reg[WLD];

    // prologue: load tile kc=0 into registers
    if (aval) a_reg = *(const float4*)(aptr);
#pragma unroll
    for (int i = 0; i < WLD; ++i)
        w_reg[i] = *(const float4*)(W + (size_t)(foff + sn + 64 * i) * K + sk);

    for (int kc = 0; kc < K; kc += KC) {
        // commit staged registers to LDS (transposed: k-major)
        As[sk + 0][sn] = a_reg.x;
        As[sk + 1][sn] = a_reg.y;
        As[sk + 2][sn] = a_reg.z;
        As[sk + 3][sn] = a_reg.w;
#pragma unroll
        for (int i = 0; i < WLD; ++i) {
            const int sm = sn + 64 * i;
            Ws[sk + 0][sm] = w_reg[i].x;
            Ws[sk + 1][sm] = w_reg[i].y;
            Ws[sk + 2][sm] = w_reg[i].z;
            Ws[sk + 3][sm] = w_reg[i].w;
        }
        __syncthreads();

        // prefetch next tile: loads drain while we compute below
        if (kc + KC < K) {
            if (aval) a_reg = *(const float4*)(aptr + kc + KC);
#pragma unroll
            for (int i = 0; i < WLD; ++i)
                w_reg[i] = *(const float4*)(W + (size_t)(foff + sn + 64 * i) * K
                                            + kc + KC + sk);
        }

#pragma unroll 4
        for (int k = 0; k < KC; ++k) {
            const float4 av = *(const float4*)&As[k][tx * 4];   // 1 b128, 2-way
            float a[TN] = {av.x, av.y, av.z, av.w};
            float w[TM];
#pragma unroll
            for (int j4 = 0; j4 < TM / 4; ++j4) {
                float4 wv = *(const float4*)&Ws[k][ty * TM + j4 * 4];  // broadcast
                w[j4 * 4 + 0] = wv.x; w[j4 * 4 + 1] = wv.y;
                w[j4 * 4 + 2] = wv.z; w[j4 * 4 + 3] = wv.w;
            }
#pragma unroll
            for (int i = 0; i < TN; ++i)
#pragma unroll
                for (int j = 0; j < TM; ++j) acc[i][j] = fmaf(a[i], w[j], acc[i][j]);
        }
        __syncthreads();
    }

#pragma unroll
    for (int i = 0; i < TN; ++i) {
        int node = nodeBase + tx * 4 + i;
        if (node < N) {
            float* cp = C + (size_t)node * M + foff + ty * TM;
#pragma unroll
            for (int j4 = 0; j4 < TM / 4; ++j4) {
                float t[4];
#pragma unroll
                for (int c = 0; c < 4; ++c) {
                    float x = acc[i][j4 * 4 + c];
                    if constexpr (BIAS) x += bias[foff + ty * TM + j4 * 4 + c];
                    if constexpr (ACT == 1) x = fmaxf(x, 0.f);
                    if constexpr (ACT == 2) x = 1.f / (1.f + __expf(-x));
                    t[c] = x;
                }
                float4 v; v.x = t[0]; v.y = t[1]; v.z = t[2]; v.w = t[3];
                *(float4*)(cp + j4 * 4) = v;
            }
        }
    }
}

// ---------------- CSR build: deterministic counting sort -------------
// bucket b = dst >> 6; count index = b*128 + r*16 + g  (r = blockIdx&7,
// g = blockIdx>>3) => bucketBase[b] = pos[b*128]. Zero global atomics.

__global__ __launch_bounds__(256) void count_k(const int* __restrict__ ei,
                                               int* __restrict__ cnt,
                                               int NB, int E) {
    __shared__ int hist[784];
    const int tid = threadIdx.x;
    for (int i = tid; i < NB; i += 256) hist[i] = 0;
    __syncthreads();
    const int chunk = (E + NBLK - 1) / NBLK;
    const int lo = blockIdx.x * chunk;
    const int hi = min(lo + chunk, E);
    for (int e = lo + tid; e < hi; e += 256) {
        int d = ei[E + e];
        atomicAdd(&hist[d >> 6], 1);
    }
    __syncthreads();
    const int r = blockIdx.x & 7, g = blockIdx.x >> 3;
    for (int i = tid; i < NB; i += 256)
        cnt[i * NBLK + r * GRP + g] = hist[i];
}

__global__ __launch_bounds__(256) void scan1(const int* __restrict__ cnt,
                                             int* __restrict__ pos,
                                             int* __restrict__ bs, int n) {
    __shared__ int s[256];
    const int t = threadIdx.x;
    const int i0 = blockIdx.x * 512 + 2 * t;
    int c0 = (i0     < n) ? cnt[i0]     : 0;
    int c1 = (i0 + 1 < n) ? cnt[i0 + 1] : 0;
    int c = c0 + c1;
    s[t] = c;
    __syncthreads();
    for (int off = 1; off < 256; off <<= 1) {
        int v = (t >= off) ? s[t - off] : 0;
        __syncthreads();
        s[t] += v;
        __syncthreads();
    }
    int excl = s[t] - c;
    if (i0     < n) pos[i0]     = excl;
    if (i0 + 1 < n) pos[i0 + 1] = excl + c0;
    if (t == 255) bs[blockIdx.x] = s[255];
}

__global__ __launch_bounds__(256) void scan_tops(int* __restrict__ bs, int nb) {
    __shared__ int s[256];
    int t = threadIdx.x;
    int v = (t < nb) ? bs[t] : 0;
    s[t] = v;
    __syncthreads();
    for (int off = 1; off < 256; off <<= 1) {
        int u = (t >= off) ? s[t - off] : 0;
        __syncthreads();
        s[t] += u;
        __syncthreads();
    }
    if (t < nb) bs[t] = s[t] - v;
}

__global__ __launch_bounds__(256) void scan2(int* __restrict__ pos,
                                             const int* __restrict__ bs,
                                             int* __restrict__ bucketBase,
                                             int n, int NB, int E) {
    const int t = threadIdx.x;
    const int i0 = blockIdx.x * 512 + 2 * t;
    const int add = bs[blockIdx.x];
#pragma unroll
    for (int c = 0; c < 2; ++c) {
        int i = i0 + c;
        if (i < n) {
            int v = pos[i] + add;
            pos[i] = v;
            if ((i & (NBLK - 1)) == 0) bucketBase[i >> 7] = v;
        }
    }
    if (blockIdx.x == 0 && t == 0) bucketBase[NB] = E;
}

__global__ __launch_bounds__(256) void place_k(const int* __restrict__ ei,
                                               const float* __restrict__ w,
                                               const int* __restrict__ pos,
                                               int2* __restrict__ ebuf,
                                               int NB, int E) {
    __shared__ int cur[784];
    const int tid = threadIdx.x;
    const int r = blockIdx.x & 7, g = blockIdx.x >> 3;
    for (int i = tid; i < NB; i += 256) cur[i] = pos[i * NBLK + r * GRP + g];
    __syncthreads();
    const int chunk = (E + NBLK - 1) / NBLK;
    const int lo = blockIdx.x * chunk;
    const int hi = min(lo + chunk, E);
    for (int e = lo + tid; e < hi; e += 256) {
        int s = ei[e];
        int d = ei[E + e];
        float wv = w[e];
        int p = atomicAdd(&cur[d >> 6], 1);  // LDS atomic
        ebuf[p] = make_int2(s | ((d & 63) << 26), __float_as_int(wv));
    }
}

__global__ __launch_bounds__(256) void bucket_build(const int2* __restrict__ ebuf,
                                                    const int* __restrict__ bucketBase,
                                                    int2* __restrict__ sn,
                                                    int* __restrict__ row,
                                                    float* __restrict__ dinv,
                                                    int N, int E) {
    __shared__ int   lh[64];
    __shared__ float ldg[64];
    __shared__ int   sc[64];
    __shared__ int   lofs[64];
    const int tid  = threadIdx.x;
    const int base = bucketBase[blockIdx.x];
    const int end  = bucketBase[blockIdx.x + 1];

    if (tid < 64) { lh[tid] = 0; ldg[tid] = 0.f; }
    __syncthreads();
    for (int i = base + tid; i < end; i += 256) {
        int2 v = ebuf[i];
        int dl = ((unsigned)v.x) >> 26;
        atomicAdd(&lh[dl], 1);
        atomicAdd(&ldg[dl], __int_as_float(v.y));
    }
    __syncthreads();
    if (tid < 64) sc[tid] = lh[tid];
    __syncthreads();
    for (int off = 1; off < 64; off <<= 1) {
        int v = (tid < 64 && tid >= off) ? sc[tid - off] : 0;
        __syncthreads();
        if (tid < 64) sc[tid] += v;
        __syncthreads();
    }
    if (tid < 64) {
        int excl = sc[tid] - lh[tid];
        int d = (blockIdx.x << 6) + tid;
        if (d < N) {
            row[d]  = base + excl;
            dinv[d] = rsqrtf(fmaxf(1.0f + ldg[tid], 1e-12f));  // + self-loop
        }
        lofs[tid] = base + excl;
    }
    __syncthreads();
    for (int i = base + tid; i < end; i += 256) {
        int2 v = ebuf[i];
        unsigned u = (unsigned)v.x;
        int dl = u >> 26;
        int s  = u & 0x03FFFFFF;
        int p  = atomicAdd(&lofs[dl], 1);
        sn[p] = make_int2(s, v.y);
    }
    if (blockIdx.x == 0 && tid == 0) row[N] = E;
}

// payload.y <- w * dinv[src]
__global__ __launch_bounds__(256) void scale_pay(int2* __restrict__ sn,
                                                 const float* __restrict__ dinv,
                                                 int E) {
    int p = blockIdx.x * 256 + threadIdx.x;
    if (p < E) {
        int2 v = sn[p];
        sn[p] = make_int2(v.x, __float_as_int(__int_as_float(v.y) * dinv[v.x]));
    }
}

// ---------------- fused GCN aggregation (gather, no atomics) ---------
// out[i] = relu( (sum_e pay_e*t[src_e] + t[i]*dinv[i]) * dinv[i] + b )
__global__ __launch_bounds__(256) void gcn_agg(const float* __restrict__ t,
                                               const int2* __restrict__ sn,
                                               const int* __restrict__ row,
                                               const float* __restrict__ dinv,
                                               const float* __restrict__ bias,
                                               float* __restrict__ out, int N) {
    const int lane = threadIdx.x & 63;
    int i = __builtin_amdgcn_readfirstlane((int)(blockIdx.x * 4) + (threadIdx.x >> 6));
    if (i >= N) return;
    float di   = dinv[i];
    float self = t[(size_t)i * 64 + lane];
    float acc  = 0.f;
    int p  = row[i];
    int pe = row[i + 1];
    for (; p + 4 <= pe; p += 4) {
        int2 v0 = sn[p];
        int2 v1 = sn[p + 1];
        int2 v2 = sn[p + 2];
        int2 v3 = sn[p + 3];
        acc += t[(size_t)v0.x * 64 + lane] * __int_as_float(v0.y);
        acc += t[(size_t)v1.x * 64 + lane] * __int_as_float(v1.y);
        acc += t[(size_t)v2.x * 64 + lane] * __int_as_float(v2.y);
        acc += t[(size_t)v3.x * 64 + lane] * __int_as_float(v3.y);
    }
    for (; p < pe; ++p) {
        int2 v = sn[p];
        acc += t[(size_t)v.x * 64 + lane] * __int_as_float(v.y);
    }
    float x = (acc + self * di) * di + bias[lane];
    out[(size_t)i * 64 + lane] = fmaxf(x, 0.f);
}

// =====================================================================
extern "C" void kernel_launch(void* const* d_in, const int* in_sizes, int n_in,
                              void* d_out, int out_size, void* d_ws, size_t ws_size,
                              hipStream_t stream) {
    const float* x      = (const float*)d_in[0];
    const int*   ei     = (const int*)d_in[1];   // int32 per harness contract
    const float* ew     = (const float*)d_in[2];
    const float* enc1_w = (const float*)d_in[3];
    const float* enc1_b = (const float*)d_in[4];
    const float* enc2_w = (const float*)d_in[5];
    const float* enc2_b = (const float*)d_in[6];
    const float* gcn1_w = (const float*)d_in[7];
    const float* gcn1_b = (const float*)d_in[8];
    const float* gcn2_w = (const float*)d_in[9];
    const float* gcn2_b = (const float*)d_in[10];
    const float* dec1_w = (const float*)d_in[11];
    const float* dec1_b = (const float*)d_in[12];
    const float* dec2_w = (const float*)d_in[13];
    const float* dec2_b = (const float*)d_in[14];

    const int N  = in_sizes[0] / 256;    // 50000
    const int E  = in_sizes[2];          // 1600000
    const int NB = (N + 63) / 64;        // 782 buckets
    const int NCNT = NB * NBLK;          // 100096 counters
    const int NS   = (NCNT + 511) / 512; // 196 scan blocks

    // workspace (~40 MB):
    //  bufA [N*128 floats]: h1 -> { sn[E] int2 | ebuf[E] int2 (=bufC) } -> h5
    //  bufB [N*64]: h2/h3/h4 ; dinv[N]; row[N+1];
    //  cnt[NCNT]; pos[NCNT]; bucketBase[NB+1]; bs[256]
    float* ws   = (float*)d_ws;
    float* bufA = ws;
    int2*  sn   = (int2*)bufA;                  // E int2 (first half of bufA)
    float* bufC = bufA + (size_t)2 * E;         // N*64 floats (second half)
    int2*  ebuf = (int2*)bufC;                  // aliases bufC during build
    float* bufB = bufA + (size_t)N * 128;       // N*64
    float* dinv = bufB + (size_t)N * 64;        // N
    int*   row  = (int*)(dinv + N);             // N+1
    int*   cnt  = row + (N + 1);                // NCNT
    int*   pos  = cnt + NCNT;                   // NCNT
    int*   bucketBase = pos + NCNT;             // NB+1
    int*   bs   = bucketBase + (NB + 1);        // 256

    const int gemmGrid = (N + 63) / 64;         // 782
    const int nBlkE    = (E + 255) / 256;       // 6250

    // encoder
    gemm_rt<256, 128, 128, 1, true><<<dim3(gemmGrid, 1), 256, 0, stream>>>(
        x, enc1_w, enc1_b, bufA, N);
    gemm_rt<128, 64, 64, 1, true><<<dim3(gemmGrid, 1), 256, 0, stream>>>(
        bufA, enc2_w, enc2_b, bufB, N);

    // CSR build, zero global atomics (shared by both GCN layers)
    count_k<<<NBLK, 256, 0, stream>>>(ei, cnt, NB, E);
    scan1<<<NS, 256, 0, stream>>>(cnt, pos, bs, NCNT);
    scan_tops<<<1, 256, 0, stream>>>(bs, NS);
    scan2<<<NS, 256, 0, stream>>>(pos, bs, bucketBase, NCNT, NB, E);
    place_k<<<NBLK, 256, 0, stream>>>(ei, ew, pos, ebuf, NB, E);
    bucket_build<<<NB, 256, 0, stream>>>(ebuf, bucketBase, sn, row, dinv, N, E);
    scale_pay<<<nBlkE, 256, 0, stream>>>(sn, dinv, E);

    // GCN layer 1
    gemm_rt<64, 64, 64, 0, false><<<dim3(gemmGrid, 1), 256, 0, stream>>>(
        bufB, gcn1_w, nullptr, bufC, N);
    gcn_agg<<<(N + 3) / 4, 256, 0, stream>>>(bufC, sn, row, dinv, gcn1_b, bufB, N);

    // GCN layer 2
    gemm_rt<64, 64, 64, 0, false><<<dim3(gemmGrid, 1), 256, 0, stream>>>(
        bufB, gcn2_w, nullptr, bufC, N);
    gcn_agg<<<(N + 3) / 4, 256, 0, stream>>>(bufC, sn, row, dinv, gcn2_b, bufB, N);

    // decoder
    gemm_rt<64, 128, 128, 1, true><<<dim3(gemmGrid, 1), 256, 0, stream>>>(
        bufB, dec1_w, dec1_b, bufA, N);
    gemm_rt<128, 128, 256, 2, true><<<dim3(gemmGrid, 2), 256, 0, stream>>>(
        bufA, dec2_w, dec2_b, (float*)d_out, N);
}